// Round 1
// 521.534 us; speedup vs baseline: 1.0364x; 1.0364x over previous
//
#include <hip/hip_runtime.h>
#include <stdint.h>
#include <stddef.h>

typedef _Float16 half_t;
typedef _Float16 half8 __attribute__((ext_vector_type(8)));
typedef float float4v __attribute__((ext_vector_type(4)));

#define D_DIM 1792
#define B_DIM 8192
#define LD D_DIM

// ---------------------------------------------------------------------------
// Async global->LDS staging of ROWS*32 fp16 tile (rows along K, NT layout).
// slot = chunk ^ ((row>>1)&3): every 8-lane b128 phase covers all 8 bank-quads
// (conflict-free — verified R2: SQ_LDS_BANK_CONFLICT 6.4e6 -> 0).
// ---------------------------------------------------------------------------
__device__ __forceinline__ void stage_rows(const half_t* __restrict__ src, int row0, int ld,
                                           int k0, half_t* dst, int nchunks, int tid) {
  for (int base = 0; base < nchunks; base += 256) {
    int ch  = base + tid;
    int row = ch >> 2, kc = ch & 3;
    int swz = kc ^ ((row >> 1) & 3);
    const half_t* g = src + (size_t)(row0 + row) * ld + k0 + swz * 8;
    half_t* l = dst + (size_t)(base + (tid & 192)) * 8;   // wave-uniform base; HW adds lane*16B
    __builtin_amdgcn_global_load_lds(
        (const __attribute__((address_space(1))) uint32_t*)(const void*)g,
        (__attribute__((address_space(3))) uint32_t*)(void*)l, 16, 0, 0);
  }
}

__device__ __forceinline__ half8 frag32(const half_t* lds, int row, int chunk) {
  int slot = chunk ^ ((row >> 1) & 3);
  return *(const half8*)(lds + row * 32 + slot * 8);
}
// 128-wide LDS rows (Us / Dinv in the solve): 2-way aliasing only (free).
__device__ __forceinline__ half8 frag128(const half_t* lds, int row, int chunk) {
  int slot = chunk ^ (row & 15);
  return *(const half8*)(lds + row * 128 + slot * 8);
}

// ---------------------------------------------------------------------------
// 1. Row-normalize U -> Vh (fp16). One block per row.
// ---------------------------------------------------------------------------
__global__ __launch_bounds__(256) void normalize_rows(const float* __restrict__ U,
                                                      half_t* __restrict__ Vh) {
  int r = blockIdx.x, t = threadIdx.x;
  float v[7];
  float s = 0.f;
#pragma unroll
  for (int i = 0; i < 7; ++i) {
    v[i] = U[(size_t)r * D_DIM + t + i * 256];
    s += v[i] * v[i];
  }
#pragma unroll
  for (int m = 32; m; m >>= 1) s += __shfl_xor(s, m);
  __shared__ float red[4];
  __shared__ float tot;
  if ((t & 63) == 0) red[t >> 6] = s;
  __syncthreads();
  if (t == 0) tot = 1.0f / sqrtf(red[0] + red[1] + red[2] + red[3]);
  __syncthreads();
  float rn = tot;
#pragma unroll
  for (int i = 0; i < 7; ++i)
    Vh[(size_t)r * D_DIM + t + i * 256] = (half_t)(v[i] * rn);
}

// ---------------------------------------------------------------------------
// 2. Transpose X (fp32, D x B) -> XT (fp16, B x D). 64x64 LDS tiles.
// ---------------------------------------------------------------------------
__global__ __launch_bounds__(256) void transpose_x(const float* __restrict__ X,
                                                   half_t* __restrict__ XT) {
  __shared__ half_t t[64][68];
  int r0 = blockIdx.x * 64, c0 = blockIdx.y * 64;
  int tid = threadIdx.x;
#pragma unroll
  for (int i = 0; i < 16; ++i) {
    int f = tid + i * 256;
    int rr = f >> 6, cc = f & 63;
    t[rr][cc] = (half_t)X[(size_t)(r0 + rr) * B_DIM + c0 + cc];
  }
  __syncthreads();
#pragma unroll
  for (int i = 0; i < 16; ++i) {
    int f = tid + i * 256;
    int cc = f >> 6, rr = f & 63;
    XT[(size_t)(c0 + cc) * D_DIM + r0 + rr] = t[rr][cc];
  }
}

// ---------------------------------------------------------------------------
// 2b. Transpose Vh (fp16, D x D) -> VhT.
// ---------------------------------------------------------------------------
__global__ __launch_bounds__(256) void transpose_h(const half_t* __restrict__ Vh,
                                                   half_t* __restrict__ VhT) {
  __shared__ half_t t[64][68];
  int r0 = blockIdx.x * 64, c0 = blockIdx.y * 64;
  int tid = threadIdx.x;
#pragma unroll
  for (int i = 0; i < 16; ++i) {
    int f = tid + i * 256;
    int rr = f >> 6, cc = f & 63;
    t[rr][cc] = Vh[(size_t)(r0 + rr) * D_DIM + c0 + cc];
  }
  __syncthreads();
#pragma unroll
  for (int i = 0; i < 16; ++i) {
    int f = tid + i * 256;
    int cc = f >> 6, rr = f & 63;
    VhT[(size_t)(c0 + cc) * D_DIM + r0 + rr] = t[rr][cc];
  }
}

// ---------------------------------------------------------------------------
// 3. Big NT MFMA GEMM: acc[m][n] = sum_k A[m][k]*B[n][k], 128x128 tile, BK=32.
//    MODE 0 (gram->T16): triangular block skip; Ch = (c<r) ? 2*acc : 0  (fp16)
//    MODE 1 (Pf build):  Ch = (r==c ? 1 : 0) - acc                      (fp16)
//    MODE 2 (final):     Cf = acc                                       (fp32)
// ---------------------------------------------------------------------------
template <int MODE>
__global__ __launch_bounds__(256) void gemm_nt(const half_t* __restrict__ A,
                                               const half_t* __restrict__ B,
                                               float* __restrict__ Cf, half_t* __restrict__ Ch,
                                               int K, int lda, int ldb, int ldc) {
  int m0 = blockIdx.y * 128, n0 = blockIdx.x * 128;
  if constexpr (MODE == 0) { if (n0 > m0) return; }   // gram: lower+diag blocks only
  __shared__ half_t sA[128 * 32];
  __shared__ half_t sB[128 * 32];
  int tid = threadIdx.x, lane = tid & 63, wave = tid >> 6;
  int ln15 = lane & 15, quad = lane >> 4;
  int wr = (wave & 1) * 64, wc = (wave >> 1) * 64;
  float4v acc[4][4] = {};
  for (int kb = 0; kb < K / 32; ++kb) {
    stage_rows(A, m0, lda, kb * 32, sA, 512, tid);
    stage_rows(B, n0, ldb, kb * 32, sB, 512, tid);
    __syncthreads();
    half8 af[4], bf[4];
#pragma unroll
    for (int i = 0; i < 4; ++i) af[i] = frag32(sA, wr + i * 16 + ln15, quad);
#pragma unroll
    for (int j = 0; j < 4; ++j) bf[j] = frag32(sB, wc + j * 16 + ln15, quad);
#pragma unroll
    for (int i = 0; i < 4; ++i)
#pragma unroll
      for (int j = 0; j < 4; ++j)
        acc[i][j] = __builtin_amdgcn_mfma_f32_16x16x32_f16(af[i], bf[j], acc[i][j], 0, 0, 0);
    __syncthreads();
  }
#pragma unroll
  for (int i = 0; i < 4; ++i)
#pragma unroll
    for (int j = 0; j < 4; ++j)
#pragma unroll
      for (int rg = 0; rg < 4; ++rg) {
        int row = m0 + wr + i * 16 + quad * 4 + rg;
        int col = n0 + wc + j * 16 + ln15;
        size_t idx = (size_t)row * ldc + col;
        float v = acc[i][j][rg];
        if constexpr (MODE == 0) Ch[idx] = (col < row) ? (half_t)(2.0f * v) : (half_t)0.0f;
        else if constexpr (MODE == 1) Ch[idx] = (half_t)(((row == col) ? 1.0f : 0.0f) - v);
        else Cf[idx] = v;
      }
}

// ---------------------------------------------------------------------------
// 4. Invert 14 diagonal 128x128 unit-lower-triangular blocks of T (from T16).
//    One wave per column; forward substitution. -> Dinv (fp16, 14x128x128)
// ---------------------------------------------------------------------------
__global__ __launch_bounds__(256) void diag_inv(const half_t* __restrict__ T16,
                                                half_t* __restrict__ Dinv) {
  int b = blockIdx.x >> 5;        // block 0..13
  int cg = blockIdx.x & 31;       // column group
  int wave = threadIdx.x >> 6, ln = threadIdx.x & 63;
  int c = cg * 4 + wave;          // this wave's column (0..127)
  __shared__ float Ls[128][128];
  __shared__ float xw[4][128];
  for (int i = 0; i < 64; ++i) {
    int f = threadIdx.x + i * 256;
    int r = f >> 7, cc = f & 127;
    Ls[r][cc] = (cc < r) ? (float)T16[(size_t)(b * 128 + r) * D_DIM + b * 128 + cc] : 0.0f;
  }
  __syncthreads();
  float xlo = (ln == 0) ? 1.f : 0.f, xhi = 0.f;
  for (int r = c + 1; r < 128; ++r) {
    float ta = 0.f;
    int j0 = c + ln, j1 = c + 64 + ln;
    if (j0 < r) ta += Ls[r][j0] * xlo;
    if (j1 < r) ta += Ls[r][j1] * xhi;
#pragma unroll
    for (int m = 32; m; m >>= 1) ta += __shfl_xor(ta, m);
    float xr = -ta;
    if (j0 == r) xlo = xr;
    if (j1 == r) xhi = xr;
    if (ln == 0) xw[wave][r] = xr;
  }
  __syncthreads();
  for (int rr = ln; rr < 128; rr += 64) {
    float val = (rr < c) ? 0.f : ((rr == c) ? 1.f : xw[wave][rr]);
    Dinv[(size_t)b * 16384 + (size_t)rr * 128 + c] = (half_t)val;
  }
}

// ---------------------------------------------------------------------------
// 5. FUSED blocked forward substitution — ONE launch. R3: the K-loop was
//    barrier-latency-bound (364 BK=32 iters, each with a vmcnt(0)-draining
//    __syncthreads ~1200cy => 182us of the 197us). Now: BK=64 (182 iters),
//    double-buffered global_load_lds staging with COUNTED vmcnt(6) + raw
//    s_barrier (loads stay in flight across the barrier; T3+T4 pattern).
//    LDS unions: Us overlays the sA dbuf, sD overlays the sB dbuf (K-loop
//    and phases 2-4 never overlap in time; 48KB total, fits static limit).
//    Panel boundaries keep __syncthreads (its vmcnt(0) drain IS the WtT
//    store->load visibility fence).
//    Per panel ib:
//      Ut[m][s] = 2*Vn[ib*128+s][m] - sum_{k<ib*128} WtT[m][k]*T16[ib*128+s][k]
//      WtT[m][ib*128+r] = sum_s Ut[m][s]*Dinv[ib][r][s]
// ---------------------------------------------------------------------------
__global__ __launch_bounds__(256) void fused_solve(const half_t* __restrict__ T16,
                                                   const half_t* __restrict__ Vh,
                                                   const half_t* __restrict__ Dinv,
                                                   half_t* __restrict__ WtT) {
  __shared__ half_t sA[2][64 * 64];    // 2 x 8KB  K-loop A dbuf; union = Us (64x128)
  __shared__ half_t sB[2][128 * 64];   // 2 x 16KB K-loop B dbuf; union = sD (128x128)
  half_t* Us = &sA[0][0];
  half_t* sD = &sB[0][0];
  int tid = threadIdx.x, lane = tid & 63, wave = tid >> 6;
  int ln15 = lane & 15, quad = lane >> 4;
  int m0 = blockIdx.x * 64;
  int wr = (wave & 1) * 32, wc = (wave >> 1) * 64;
  for (int ib = 0; ib < 14; ++ib) {
    // drain prev panel's WtT stores (vmcnt(0)) + free Us/sD regions for staging
    __syncthreads();
    float4v acc[2][4] = {};
    int Ksteps = ib * 2;               // BK=64 steps
    if (Ksteps > 0) {
      // prologue: stage buf0 (6 global_load_lds per thread)
      stage_rows(WtT, m0, D_DIM, 0, &sA[0][0], 256, tid);
      stage_rows(WtT, m0, D_DIM, 32, &sA[0][0] + 2048, 256, tid);
      stage_rows(T16, ib * 128, D_DIM, 0, &sB[0][0], 512, tid);
      stage_rows(T16, ib * 128, D_DIM, 32, &sB[0][0] + 4096, 512, tid);
      for (int kb = 0; kb < Ksteps; ++kb) {
        int cur = kb & 1;
        if (kb + 1 < Ksteps) {
          int nxt = cur ^ 1, k0 = (kb + 1) * 64;
          stage_rows(WtT, m0, D_DIM, k0, &sA[nxt][0], 256, tid);
          stage_rows(WtT, m0, D_DIM, k0 + 32, &sA[nxt][0] + 2048, 256, tid);
          stage_rows(T16, ib * 128, D_DIM, k0, &sB[nxt][0], 512, tid);
          stage_rows(T16, ib * 128, D_DIM, k0 + 32, &sB[nxt][0] + 4096, 512, tid);
          // my buf[cur] loads done when only the 6 just-issued remain (FIFO retire)
          asm volatile("s_waitcnt vmcnt(6)" ::: "memory");
        } else {
          asm volatile("s_waitcnt vmcnt(0)" ::: "memory");
        }
        __builtin_amdgcn_s_barrier();        // all waves' buf[cur] loads landed
        __builtin_amdgcn_sched_barrier(0);   // pin ds_reads below the barrier
        half8 af[2], bf[4];
#pragma unroll
        for (int q = 0; q < 2; ++q) {
          const half_t* pa = &sA[cur][0] + q * 2048;
          const half_t* pb = &sB[cur][0] + q * 4096;
#pragma unroll
          for (int i = 0; i < 2; ++i) af[i] = frag32(pa, wr + i * 16 + ln15, quad);
#pragma unroll
          for (int j = 0; j < 4; ++j) bf[j] = frag32(pb, wc + j * 16 + ln15, quad);
#pragma unroll
          for (int i = 0; i < 2; ++i)
#pragma unroll
            for (int j = 0; j < 4; ++j)
              acc[i][j] = __builtin_amdgcn_mfma_f32_16x16x32_f16(af[i], bf[j], acc[i][j], 0, 0, 0);
        }
        __builtin_amdgcn_sched_barrier(0);   // pin ds_reads above the barrier
        __builtin_amdgcn_s_barrier();        // buf[cur^1] now safe to overwrite
      }
    }
    // phase 2: Ut = 2*VnT - acc  -> Us (A-operand layout, swizzled)
    // (last K-iter's trailing barrier freed the sA region for Us writes)
#pragma unroll
    for (int i = 0; i < 2; ++i)
#pragma unroll
      for (int j = 0; j < 4; ++j)
#pragma unroll
        for (int rg = 0; rg < 4; ++rg) {
          int rl = wr + i * 16 + quad * 4 + rg;     // local m
          int cl = wc + j * 16 + ln15;              // local s (panel row)
          float vn = (float)Vh[(size_t)(ib * 128 + cl) * D_DIM + m0 + rl];
          float u = 2.f * vn - acc[i][j][rg];
          int sc = cl >> 3, off = cl & 7;
          Us[rl * 128 + ((sc ^ (rl & 15)) << 3) + off] = (half_t)u;
        }
    // phase 3: stage Dinv block ib (global-side swizzle for 128-wide rows)
    for (int it = 0; it < 8; ++it) {
      int ch = it * 256 + tid;
      int row = ch >> 4, sc = ch & 15;
      const half_t* g = Dinv + (size_t)ib * 16384 + (size_t)row * 128 + ((sc ^ (row & 15)) << 3);
      half_t* l = sD + (size_t)(it * 256 + (tid & 192)) * 8;
      __builtin_amdgcn_global_load_lds(
          (const __attribute__((address_space(1))) uint32_t*)(const void*)g,
          (__attribute__((address_space(3))) uint32_t*)(void*)l, 16, 0, 0);
    }
    __syncthreads();   // full drain: sD loads + Us ds_writes visible to all
    // phase 4: WtT-panel = Ut * Dinv^T  (K=128)
    float4v a2[2][4] = {};
#pragma unroll
    for (int kk = 0; kk < 4; ++kk) {
      half8 af[2], bf[4];
#pragma unroll
      for (int i = 0; i < 2; ++i) af[i] = frag128(Us, wr + i * 16 + ln15, kk * 4 + quad);
#pragma unroll
      for (int j = 0; j < 4; ++j) bf[j] = frag128(sD, wc + j * 16 + ln15, kk * 4 + quad);
#pragma unroll
      for (int i = 0; i < 2; ++i)
#pragma unroll
        for (int j = 0; j < 4; ++j)
          a2[i][j] = __builtin_amdgcn_mfma_f32_16x16x32_f16(af[i], bf[j], a2[i][j], 0, 0, 0);
    }
#pragma unroll
    for (int i = 0; i < 2; ++i)
#pragma unroll
      for (int j = 0; j < 4; ++j)
#pragma unroll
        for (int rg = 0; rg < 4; ++rg) {
          int rl = wr + i * 16 + quad * 4 + rg;
          int cl = wc + j * 16 + ln15;
          WtT[(size_t)(m0 + rl) * D_DIM + ib * 128 + cl] = (half_t)a2[i][j][rg];
        }
  }
}

// ---------------------------------------------------------------------------
extern "C" void kernel_launch(void* const* d_in, const int* in_sizes, int n_in,
                              void* d_out, int out_size, void* d_ws, size_t ws_size,
                              hipStream_t stream) {
  (void)in_sizes; (void)n_in; (void)out_size; (void)ws_size;
  const float* X = (const float*)d_in[0];   // (1792, 8192) fp32
  const float* U = (const float*)d_in[1];   // (1792, 1792) fp32
  float* out = (float*)d_out;               // (1792, 8192) fp32

  char* ws = (char*)d_ws;
  half_t* XT   = (half_t*)(ws);                    // 29,360,128 B
  half_t* Vh   = (half_t*)(ws + 29360128);         //  6,422,528 B
  half_t* VhT  = (half_t*)(ws + 35782656);         //  6,422,528 B
  half_t* T16  = (half_t*)(ws + 42205184);         //  6,422,528 B
  half_t* WtT  = (half_t*)(ws + 48627712);         //  6,422,528 B
  half_t* Dinv = (half_t*)(ws + 55050240);         //    458,752 B
  half_t* Pf   = (half_t*)(ws + 55508992);         //  6,422,528 B  (total ~62 MB)

  normalize_rows<<<dim3(D_DIM), dim3(256), 0, stream>>>(U, Vh);
  transpose_x<<<dim3(D_DIM / 64, B_DIM / 64), dim3(256), 0, stream>>>(X, XT);
  // T16 = 2*strict_tril(Vn Vn^T) directly (gram fused with build_T16; fp32 G gone)
  gemm_nt<0><<<dim3(14, 14), dim3(256), 0, stream>>>(Vh, Vh, nullptr, T16,
                                                     D_DIM, D_DIM, D_DIM, D_DIM);
  transpose_h<<<dim3(28, 28), dim3(256), 0, stream>>>(Vh, VhT);
  diag_inv<<<dim3(448), dim3(256), 0, stream>>>(T16, Dinv);
  // one-launch blocked forward substitution: WtT = (T^{-1} 2Vn)^T
  fused_solve<<<dim3(28), dim3(256), 0, stream>>>(T16, Vh, Dinv, WtT);
  // Pf = I - Wt^T Vn :  Pf[m][n] = delta(m,n) - sum_k WtT[m][k]*VhT[n][k]
  gemm_nt<1><<<dim3(14, 14), dim3(256), 0, stream>>>(WtT, VhT, nullptr, Pf,
                                                     D_DIM, D_DIM, D_DIM, D_DIM);
  // out = Pf X :  out[i][j] = sum_k Pf[i][k]*XT[j][k]
  gemm_nt<2><<<dim3(64, 14), dim3(256), 0, stream>>>(Pf, XT, out, nullptr,
                                                     D_DIM, D_DIM, D_DIM, B_DIM);
}

// Round 3
// 503.842 us; speedup vs baseline: 1.0728x; 1.0351x over previous
//
#include <hip/hip_runtime.h>
#include <stdint.h>
#include <stddef.h>

typedef _Float16 half_t;
typedef _Float16 half8 __attribute__((ext_vector_type(8)));
typedef float float4v __attribute__((ext_vector_type(4)));

#define D_DIM 1792
#define B_DIM 8192
#define LD D_DIM

// ---------------------------------------------------------------------------
// Async global->LDS staging of ROWS*32 fp16 tile (rows along K, NT layout).
// slot = chunk ^ ((row>>1)&3): every 8-lane b128 phase covers all 8 bank-quads
// (conflict-free — verified: SQ_LDS_BANK_CONFLICT 6.4e6 -> 0).  [gemm_nt path]
// ---------------------------------------------------------------------------
__device__ __forceinline__ void stage_rows(const half_t* __restrict__ src, int row0, int ld,
                                           int k0, half_t* dst, int nchunks, int tid) {
  for (int base = 0; base < nchunks; base += 256) {
    int ch  = base + tid;
    int row = ch >> 2, kc = ch & 3;
    int swz = kc ^ ((row >> 1) & 3);
    const half_t* g = src + (size_t)(row0 + row) * ld + k0 + swz * 8;
    half_t* l = dst + (size_t)(base + (tid & 192)) * 8;   // wave-uniform base; HW adds lane*16B
    __builtin_amdgcn_global_load_lds(
        (const __attribute__((address_space(1))) uint32_t*)(const void*)g,
        (__attribute__((address_space(3))) uint32_t*)(void*)l, 16, 0, 0);
  }
}

// ---------------------------------------------------------------------------
// R3: FULL-LINE staging for fused_solve. Tile rows are 64 halves (128B) wide,
// so each global row contributes exactly one aligned 128B L2 line (the old
// 32-wide layout split every row into two 64B half-line transactions — a
// CU<->L2 transaction floor). Swizzle slot = kc ^ (row&7): within each 8-lane
// b128 phase the 8 slots are distinct -> all 8 bank-quads -> conflict-free.
// LDS dest stays linear in chunk (global-side pre-swizzle + same swizzle on
// the read side — both-sides-or-neither rule).
// ---------------------------------------------------------------------------
__device__ __forceinline__ void stage_rows64(const half_t* __restrict__ src, int row0, int ld,
                                             int k0, half_t* dst, int nchunks, int tid) {
  for (int base = 0; base < nchunks; base += 256) {
    int ch  = base + tid;
    int row = ch >> 3, kc = ch & 7;
    int swz = kc ^ (row & 7);
    const half_t* g = src + (size_t)(row0 + row) * ld + k0 + swz * 8;
    half_t* l = dst + (size_t)(base + (tid & 192)) * 8;
    __builtin_amdgcn_global_load_lds(
        (const __attribute__((address_space(1))) uint32_t*)(const void*)g,
        (__attribute__((address_space(3))) uint32_t*)(void*)l, 16, 0, 0);
  }
}

__device__ __forceinline__ half8 frag32(const half_t* lds, int row, int chunk) {
  int slot = chunk ^ ((row >> 1) & 3);
  return *(const half8*)(lds + row * 32 + slot * 8);
}
__device__ __forceinline__ half8 frag64(const half_t* lds, int row, int chunk) {
  int slot = chunk ^ (row & 7);
  return *(const half8*)(lds + row * 64 + slot * 8);
}
// 128-wide LDS rows (Us / Dinv in the solve): 2-way aliasing only (free).
__device__ __forceinline__ half8 frag128(const half_t* lds, int row, int chunk) {
  int slot = chunk ^ (row & 15);
  return *(const half8*)(lds + row * 128 + slot * 8);
}

// ---------------------------------------------------------------------------
// 1. Row-normalize U -> Vh (fp16). One block per row.
// ---------------------------------------------------------------------------
__global__ __launch_bounds__(256) void normalize_rows(const float* __restrict__ U,
                                                      half_t* __restrict__ Vh) {
  int r = blockIdx.x, t = threadIdx.x;
  float v[7];
  float s = 0.f;
#pragma unroll
  for (int i = 0; i < 7; ++i) {
    v[i] = U[(size_t)r * D_DIM + t + i * 256];
    s += v[i] * v[i];
  }
#pragma unroll
  for (int m = 32; m; m >>= 1) s += __shfl_xor(s, m);
  __shared__ float red[4];
  __shared__ float tot;
  if ((t & 63) == 0) red[t >> 6] = s;
  __syncthreads();
  if (t == 0) tot = 1.0f / sqrtf(red[0] + red[1] + red[2] + red[3]);
  __syncthreads();
  float rn = tot;
#pragma unroll
  for (int i = 0; i < 7; ++i)
    Vh[(size_t)r * D_DIM + t + i * 256] = (half_t)(v[i] * rn);
}

// ---------------------------------------------------------------------------
// 2. Transpose X (fp32, D x B) -> XT (fp16, B x D). 64x64 LDS tiles.
// ---------------------------------------------------------------------------
__global__ __launch_bounds__(256) void transpose_x(const float* __restrict__ X,
                                                   half_t* __restrict__ XT) {
  __shared__ half_t t[64][68];
  int r0 = blockIdx.x * 64, c0 = blockIdx.y * 64;
  int tid = threadIdx.x;
#pragma unroll
  for (int i = 0; i < 16; ++i) {
    int f = tid + i * 256;
    int rr = f >> 6, cc = f & 63;
    t[rr][cc] = (half_t)X[(size_t)(r0 + rr) * B_DIM + c0 + cc];
  }
  __syncthreads();
#pragma unroll
  for (int i = 0; i < 16; ++i) {
    int f = tid + i * 256;
    int cc = f >> 6, rr = f & 63;
    XT[(size_t)(c0 + cc) * D_DIM + r0 + rr] = t[rr][cc];
  }
}

// ---------------------------------------------------------------------------
// 2b. Transpose Vh (fp16, D x D) -> VhT.
// ---------------------------------------------------------------------------
__global__ __launch_bounds__(256) void transpose_h(const half_t* __restrict__ Vh,
                                                   half_t* __restrict__ VhT) {
  __shared__ half_t t[64][68];
  int r0 = blockIdx.x * 64, c0 = blockIdx.y * 64;
  int tid = threadIdx.x;
#pragma unroll
  for (int i = 0; i < 16; ++i) {
    int f = tid + i * 256;
    int rr = f >> 6, cc = f & 63;
    t[rr][cc] = Vh[(size_t)(r0 + rr) * D_DIM + c0 + cc];
  }
  __syncthreads();
#pragma unroll
  for (int i = 0; i < 16; ++i) {
    int f = tid + i * 256;
    int cc = f >> 6, rr = f & 63;
    VhT[(size_t)(c0 + cc) * D_DIM + r0 + rr] = t[rr][cc];
  }
}

// ---------------------------------------------------------------------------
// 3. Big NT MFMA GEMM: acc[m][n] = sum_k A[m][k]*B[n][k], 128x128 tile, BK=32.
//    MODE 0 (gram->T16): triangular block skip; Ch = (c<r) ? 2*acc : 0  (fp16)
//    MODE 1 (Pf build):  Ch = (r==c ? 1 : 0) - acc                      (fp16)
//    MODE 2 (final):     Cf = acc                                       (fp32)
// ---------------------------------------------------------------------------
template <int MODE>
__global__ __launch_bounds__(256) void gemm_nt(const half_t* __restrict__ A,
                                               const half_t* __restrict__ B,
                                               float* __restrict__ Cf, half_t* __restrict__ Ch,
                                               int K, int lda, int ldb, int ldc) {
  int m0 = blockIdx.y * 128, n0 = blockIdx.x * 128;
  if constexpr (MODE == 0) { if (n0 > m0) return; }   // gram: lower+diag blocks only
  __shared__ half_t sA[128 * 32];
  __shared__ half_t sB[128 * 32];
  int tid = threadIdx.x, lane = tid & 63, wave = tid >> 6;
  int ln15 = lane & 15, quad = lane >> 4;
  int wr = (wave & 1) * 64, wc = (wave >> 1) * 64;
  float4v acc[4][4] = {};
  for (int kb = 0; kb < K / 32; ++kb) {
    stage_rows(A, m0, lda, kb * 32, sA, 512, tid);
    stage_rows(B, n0, ldb, kb * 32, sB, 512, tid);
    __syncthreads();
    half8 af[4], bf[4];
#pragma unroll
    for (int i = 0; i < 4; ++i) af[i] = frag32(sA, wr + i * 16 + ln15, quad);
#pragma unroll
    for (int j = 0; j < 4; ++j) bf[j] = frag32(sB, wc + j * 16 + ln15, quad);
#pragma unroll
    for (int i = 0; i < 4; ++i)
#pragma unroll
      for (int j = 0; j < 4; ++j)
        acc[i][j] = __builtin_amdgcn_mfma_f32_16x16x32_f16(af[i], bf[j], acc[i][j], 0, 0, 0);
    __syncthreads();
  }
#pragma unroll
  for (int i = 0; i < 4; ++i)
#pragma unroll
    for (int j = 0; j < 4; ++j)
#pragma unroll
      for (int rg = 0; rg < 4; ++rg) {
        int row = m0 + wr + i * 16 + quad * 4 + rg;
        int col = n0 + wc + j * 16 + ln15;
        size_t idx = (size_t)row * ldc + col;
        float v = acc[i][j][rg];
        if constexpr (MODE == 0) Ch[idx] = (col < row) ? (half_t)(2.0f * v) : (half_t)0.0f;
        else if constexpr (MODE == 1) Ch[idx] = (half_t)(((row == col) ? 1.0f : 0.0f) - v);
        else Cf[idx] = v;
      }
}

// ---------------------------------------------------------------------------
// 4. Invert 14 diagonal 128x128 unit-lower-triangular blocks of T (from T16).
//    One wave per column; forward substitution. -> Dinv (fp16, 14x128x128)
// ---------------------------------------------------------------------------
__global__ __launch_bounds__(256) void diag_inv(const half_t* __restrict__ T16,
                                                half_t* __restrict__ Dinv) {
  int b = blockIdx.x >> 5;        // block 0..13
  int cg = blockIdx.x & 31;       // column group
  int wave = threadIdx.x >> 6, ln = threadIdx.x & 63;
  int c = cg * 4 + wave;          // this wave's column (0..127)
  __shared__ float Ls[128][128];
  __shared__ float xw[4][128];
  for (int i = 0; i < 64; ++i) {
    int f = threadIdx.x + i * 256;
    int r = f >> 7, cc = f & 127;
    Ls[r][cc] = (cc < r) ? (float)T16[(size_t)(b * 128 + r) * D_DIM + b * 128 + cc] : 0.0f;
  }
  __syncthreads();
  float xlo = (ln == 0) ? 1.f : 0.f, xhi = 0.f;
  for (int r = c + 1; r < 128; ++r) {
    float ta = 0.f;
    int j0 = c + ln, j1 = c + 64 + ln;
    if (j0 < r) ta += Ls[r][j0] * xlo;
    if (j1 < r) ta += Ls[r][j1] * xhi;
#pragma unroll
    for (int m = 32; m; m >>= 1) ta += __shfl_xor(ta, m);
    float xr = -ta;
    if (j0 == r) xlo = xr;
    if (j1 == r) xhi = xr;
    if (ln == 0) xw[wave][r] = xr;
  }
  __syncthreads();
  for (int rr = ln; rr < 128; rr += 64) {
    float val = (rr < c) ? 0.f : ((rr == c) ? 1.f : xw[wave][rr]);
    Dinv[(size_t)b * 16384 + (size_t)rr * 128 + c] = (half_t)val;
  }
}

// ---------------------------------------------------------------------------
// 5. FUSED blocked forward substitution — ONE launch.
//    R3 (this round): all-STATIC LDS (144KB: 96KB ring + Us 16KB + sD 32KB;
//    no hipFuncSetAttribute / dynamic-LDS — prime suspects for R2's container
//    crash). Depth-4 staging ring (PDIST=3, counted vmcnt 18/12/6/0) with
//    FULL-LINE staging (stage_rows64: 128B/row, one L2 line per row — the old
//    32-wide layout cost 2x half-line transactions/iter). Dinv staging and
//    VhT fragment loads hoisted to panel top: both are K-loop-independent, so
//    their latency hides under the whole K-loop (phase 3 eliminated).
//    Per panel ib:
//      Ut[m][s] = 2*Vn[ib*128+s][m] - sum_{k<ib*128} WtT[m][k]*T16[ib*128+s][k]
//      WtT[m][ib*128+r] = sum_s Ut[m][s]*Dinv[ib][r][s]
// ---------------------------------------------------------------------------
#define NBUF 4
#define PDIST 3
// per-buffer (halves): sA 64x64 = 4096, sB 128x64 = 8192 -> 12288 (24KB)
#define BUF_HALVES 12288

__global__ __launch_bounds__(256) void fused_solve(const half_t* __restrict__ T16,
                                                   const half_t* __restrict__ VhT,
                                                   const half_t* __restrict__ Dinv,
                                                   half_t* __restrict__ WtT) {
  __shared__ half_t ring[NBUF * BUF_HALVES];   // 96KB staging ring
  __shared__ half_t Us[64 * 128];              // 16KB (phase 2 -> 4)
  __shared__ half_t sD[128 * 128];             // 32KB (staged at panel top)
  int tid = threadIdx.x, lane = tid & 63, wave = tid >> 6;
  int ln15 = lane & 15, quad = lane >> 4;
  int m0 = blockIdx.x * 64;
  int wr = (wave & 1) * 32, wc = (wave >> 1) * 64;
  for (int ib = 0; ib < 14; ++ib) {
    // drain prev panel's WtT stores (vmcnt0) + phase-4 LDS reads; frees sD/ring
    __syncthreads();
    // --- hoisted per-panel loads (K-loop-independent; latency hides under it)
    float vnf[2][4][4];
#pragma unroll
    for (int i = 0; i < 2; ++i)
#pragma unroll
      for (int j = 0; j < 4; ++j)
#pragma unroll
        for (int rg = 0; rg < 4; ++rg)
          vnf[i][j][rg] = (float)VhT[(size_t)(m0 + wr + i * 16 + quad * 4 + rg) * D_DIM
                                     + ib * 128 + wc + j * 16 + ln15];
    // stage Dinv block ib -> sD (global-side swizzle for 128-wide rows)
    for (int it = 0; it < 8; ++it) {
      int ch = it * 256 + tid;
      int row = ch >> 4, sc = ch & 15;
      const half_t* g = Dinv + (size_t)ib * 16384 + (size_t)row * 128 + ((sc ^ (row & 15)) << 3);
      half_t* l = sD + (size_t)(it * 256 + (tid & 192)) * 8;
      __builtin_amdgcn_global_load_lds(
          (const __attribute__((address_space(1))) uint32_t*)(const void*)g,
          (__attribute__((address_space(3))) uint32_t*)(void*)l, 16, 0, 0);
    }
    __builtin_amdgcn_sched_barrier(0);   // keep hoisted loads above the K-loop
    float4v acc[2][4] = {};
    int Ksteps = ib * 2;               // BK=64 steps
    if (Ksteps > 0) {
      // prologue: fill up to PDIST buffers ahead (6 loads/thread each)
      int npre = Ksteps < PDIST ? Ksteps : PDIST;
      for (int p = 0; p < npre; ++p) {
        half_t* bA = ring + p * BUF_HALVES;
        half_t* bB = bA + 4096;
        int k0 = p * 64;
        stage_rows64(WtT, m0, D_DIM, k0, bA, 512, tid);
        stage_rows64(T16, ib * 128, D_DIM, k0, bB, 1024, tid);
      }
      for (int kb = 0; kb < Ksteps; ++kb) {
        if (kb + PDIST < Ksteps) {
          int slot = (kb + PDIST) % NBUF, k0 = (kb + PDIST) * 64;
          half_t* bA = ring + slot * BUF_HALVES;
          half_t* bB = bA + 4096;
          stage_rows64(WtT, m0, D_DIM, k0, bA, 512, tid);
          stage_rows64(T16, ib * 128, D_DIM, k0, bB, 1024, tid);
        }
        // buffers in flight ahead of kb = min(Ksteps-1-kb, PDIST); 6 loads each.
        // (early iters also retire the older hoisted VhT/Dinv loads — harmless)
        int R = Ksteps - 1 - kb;
        if (R >= 3)      asm volatile("s_waitcnt vmcnt(18)" ::: "memory");
        else if (R == 2) asm volatile("s_waitcnt vmcnt(12)" ::: "memory");
        else if (R == 1) asm volatile("s_waitcnt vmcnt(6)"  ::: "memory");
        else             asm volatile("s_waitcnt vmcnt(0)"  ::: "memory");
        __builtin_amdgcn_s_barrier();        // all waves' buf[kb] loads landed
        __builtin_amdgcn_sched_barrier(0);   // pin ds_reads below the barrier
        half_t* cA = ring + (kb % NBUF) * BUF_HALVES;
        half_t* cB = cA + 4096;
        half8 af[2], bf[4];
#pragma unroll
        for (int q = 0; q < 2; ++q) {
#pragma unroll
          for (int i = 0; i < 2; ++i) af[i] = frag64(cA, wr + i * 16 + ln15, q * 4 + quad);
#pragma unroll
          for (int j = 0; j < 4; ++j) bf[j] = frag64(cB, wc + j * 16 + ln15, q * 4 + quad);
#pragma unroll
          for (int i = 0; i < 2; ++i)
#pragma unroll
            for (int j = 0; j < 4; ++j)
              acc[i][j] = __builtin_amdgcn_mfma_f32_16x16x32_f16(af[i], bf[j], acc[i][j], 0, 0, 0);
        }
        __builtin_amdgcn_sched_barrier(0);   // pin ds_reads above the barrier
        __builtin_amdgcn_s_barrier();        // buf[kb] now safe to overwrite
      }
    }
    // phase 2: Ut = 2*VnT - acc  -> Us (A-operand layout, swizzled)
#pragma unroll
    for (int i = 0; i < 2; ++i)
#pragma unroll
      for (int j = 0; j < 4; ++j)
#pragma unroll
        for (int rg = 0; rg < 4; ++rg) {
          int rl = wr + i * 16 + quad * 4 + rg;     // local m
          int cl = wc + j * 16 + ln15;              // local s (panel row)
          float u = 2.f * vnf[i][j][rg] - acc[i][j][rg];
          int sc = cl >> 3, off = cl & 7;
          Us[rl * 128 + ((sc ^ (rl & 15)) << 3) + off] = (half_t)u;
        }
    __syncthreads();   // full drain: sD loads (vmcnt) + Us ds_writes visible
    // phase 4: WtT-panel = Ut * Dinv^T  (K=128)
    float4v a2[2][4] = {};
#pragma unroll
    for (int kk = 0; kk < 4; ++kk) {
      half8 af[2], bf[4];
#pragma unroll
      for (int i = 0; i < 2; ++i) af[i] = frag128(Us, wr + i * 16 + ln15, kk * 4 + quad);
#pragma unroll
      for (int j = 0; j < 4; ++j) bf[j] = frag128(sD, wc + j * 16 + ln15, kk * 4 + quad);
#pragma unroll
      for (int i = 0; i < 2; ++i)
#pragma unroll
        for (int j = 0; j < 4; ++j)
          a2[i][j] = __builtin_amdgcn_mfma_f32_16x16x32_f16(af[i], bf[j], a2[i][j], 0, 0, 0);
    }
#pragma unroll
    for (int i = 0; i < 2; ++i)
#pragma unroll
      for (int j = 0; j < 4; ++j)
#pragma unroll
        for (int rg = 0; rg < 4; ++rg) {
          int rl = wr + i * 16 + quad * 4 + rg;
          int cl = wc + j * 16 + ln15;
          WtT[(size_t)(m0 + rl) * D_DIM + ib * 128 + cl] = (half_t)a2[i][j][rg];
        }
  }
}

// ---------------------------------------------------------------------------
extern "C" void kernel_launch(void* const* d_in, const int* in_sizes, int n_in,
                              void* d_out, int out_size, void* d_ws, size_t ws_size,
                              hipStream_t stream) {
  (void)in_sizes; (void)n_in; (void)out_size; (void)ws_size;
  const float* X = (const float*)d_in[0];   // (1792, 8192) fp32
  const float* U = (const float*)d_in[1];   // (1792, 1792) fp32
  float* out = (float*)d_out;               // (1792, 8192) fp32

  char* ws = (char*)d_ws;
  half_t* XT   = (half_t*)(ws);                    // 29,360,128 B
  half_t* Vh   = (half_t*)(ws + 29360128);         //  6,422,528 B
  half_t* VhT  = (half_t*)(ws + 35782656);         //  6,422,528 B
  half_t* T16  = (half_t*)(ws + 42205184);         //  6,422,528 B
  half_t* WtT  = (half_t*)(ws + 48627712);         //  6,422,528 B
  half_t* Dinv = (half_t*)(ws + 55050240);         //    458,752 B
  half_t* Pf   = (half_t*)(ws + 55508992);         //  6,422,528 B  (total ~62 MB)

  normalize_rows<<<dim3(D_DIM), dim3(256), 0, stream>>>(U, Vh);
  transpose_x<<<dim3(D_DIM / 64, B_DIM / 64), dim3(256), 0, stream>>>(X, XT);
  // T16 = 2*strict_tril(Vn Vn^T) directly (gram fused with build_T16; fp32 G gone)
  gemm_nt<0><<<dim3(14, 14), dim3(256), 0, stream>>>(Vh, Vh, nullptr, T16,
                                                     D_DIM, D_DIM, D_DIM, D_DIM);
  transpose_h<<<dim3(28, 28), dim3(256), 0, stream>>>(Vh, VhT);
  diag_inv<<<dim3(448), dim3(256), 0, stream>>>(T16, Dinv);
  // one-launch blocked forward substitution: WtT = (T^{-1} 2Vn)^T
  fused_solve<<<dim3(28), dim3(256), 0, stream>>>(T16, VhT, Dinv, WtT);
  // Pf = I - Wt^T Vn :  Pf[m][n] = delta(m,n) - sum_k WtT[m][k]*VhT[n][k]
  gemm_nt<1><<<dim3(14, 14), dim3(256), 0, stream>>>(WtT, VhT, nullptr, Pf,
                                                     D_DIM, D_DIM, D_DIM, D_DIM);
  // out = Pf X :  out[i][j] = sum_k Pf[i][k]*XT[j][k]
  gemm_nt<2><<<dim3(64, 14), dim3(256), 0, stream>>>(Pf, XT, out, nullptr,
                                                     D_DIM, D_DIM, D_DIM, B_DIM);
}